// Round 6
// baseline (277.022 us; speedup 1.0000x reference)
//
#include <hip/hip_runtime.h>

typedef float  f32x4  __attribute__((ext_vector_type(4)));
typedef __bf16 bf16x8 __attribute__((ext_vector_type(8)));
typedef __bf16 bf16x4 __attribute__((ext_vector_type(4)));

#define D_MODEL 512
#define SEQ     2048
#define BATCH   8
#define ROWS    (BATCH * SEQ)   // 16384

// async 16B global -> LDS (each lane deposits at lds_base + lane*16B)
#define ASYNC_COPY16(dst_lds, src_glb)                                          \
  __builtin_amdgcn_global_load_lds(                                             \
      (const __attribute__((address_space(1))) void*)(src_glb),                 \
      (__attribute__((address_space(3))) void*)(dst_lds), 16, 0, 0)

// ------------------------------------------------------------ fused converts
// flat 1D grid, exact ranges:
// [0,8192) x1->x1b  [8192,16384) x2->x2b  [16384,20480) exp(posb)->expBb
// [20480,21248) Wq|Wk|Wv->wb  [21248,21254) bq|bk|bv->bcat
__global__ void cvt_all_kernel(const float* __restrict__ x1,
                               const float* __restrict__ x2,
                               const float* __restrict__ posb,
                               const float* __restrict__ Wq,
                               const float* __restrict__ Wk,
                               const float* __restrict__ Wv,
                               const float* __restrict__ bq,
                               const float* __restrict__ bk,
                               const float* __restrict__ bv,
                               __bf16* __restrict__ x1b, __bf16* __restrict__ x2b,
                               __bf16* __restrict__ expBb, __bf16* __restrict__ wb,
                               float* __restrict__ bcat)
{
  const int blk = blockIdx.x;
  if (blk < 16384) {
    const float* in = (blk < 8192) ? x1 : x2;
    __bf16* out = (blk < 8192) ? x1b : x2b;
    const int i = (blk & 8191) * 256 + threadIdx.x;
    float4 v = ((const float4*)in)[i];
    bf16x4 o = { (__bf16)v.x, (__bf16)v.y, (__bf16)v.z, (__bf16)v.w };
    ((bf16x4*)out)[i] = o;
  } else if (blk < 20480) {
    const int i = (blk - 16384) * 256 + threadIdx.x;
    float4 v = ((const float4*)posb)[i];
    bf16x4 o = { (__bf16)__expf(v.x), (__bf16)__expf(v.y),
                 (__bf16)__expf(v.z), (__bf16)__expf(v.w) };
    ((bf16x4*)expBb)[i] = o;
  } else if (blk < 21248) {
    const int i = (blk - 20480) * 256 + threadIdx.x;
    const int nW4 = D_MODEL * D_MODEL / 4;
    const float* src = (i < nW4) ? Wq : (i < 2 * nW4) ? Wk : Wv;
    const int ii = i - ((i < nW4) ? 0 : (i < 2 * nW4) ? nW4 : 2 * nW4);
    float4 v = ((const float4*)src)[ii];
    bf16x4 o = { (__bf16)v.x, (__bf16)v.y, (__bf16)v.z, (__bf16)v.w };
    ((bf16x4*)wb)[i] = o;
  } else {
    const int t = (blk - 21248) * 256 + threadIdx.x;   // 0..1535
    float v = (t < 512) ? bq[t] : (t < 1024) ? bk[t - 512] : bv[t - 1024];
    bcat[t] = v;
  }
}

// ------------------------------------------------------------- QKV GEMM
// C[16384,1536] = A*[Wq;Wk;Wv]^T + bcat; A = x1b for cols<1024, x2b else.
// 256x128 tile, BK=64, 4 waves in 2x2 (each wave 128M x 64N, acc 8x4),
// XOR-swizzled global_load_lds staging. 8 K-iters (K=512).
__global__ __launch_bounds__(256, 2) void qkv_gemm_kernel(
    const __bf16* __restrict__ x1b, const __bf16* __restrict__ x2b,
    const __bf16* __restrict__ wb, const float* __restrict__ bcat,
    __bf16* __restrict__ sigq, __bf16* __restrict__ kb,
    __bf16* __restrict__ vb)
{
  __shared__ __align__(16) __bf16 As[256 * 64];   // 32 KB
  __shared__ __align__(16) __bf16 Bs[128 * 64];   // 16 KB

  const int K = D_MODEL;
  const int tid  = threadIdx.x;
  const int wave = tid >> 6;
  const int lane = tid & 63;
  const int quad = lane >> 4;
  const int l16  = lane & 15;
  const int wm   = (wave >> 1) * 128;
  const int wn   = (wave & 1) * 64;
  const int m0 = blockIdx.x * 256;
  const int n0 = blockIdx.y * 128;          // 0..1535 (row into wb)
  const int l8r = lane >> 3;
  const int scol = ((lane & 7) ^ l8r) * 8;

  const __bf16* A = (blockIdx.y < 8) ? x1b : x2b;
  const __bf16* gA = A  + (long long)(m0 + wave * 8 + l8r) * K + scol;
  const __bf16* gB = wb + (long long)(n0 + wave * 8 + l8r) * K + scol;

  f32x4 acc[8][4];
  #pragma unroll
  for (int i = 0; i < 8; ++i)
    #pragma unroll
    for (int j = 0; j < 4; ++j) acc[i][j] = (f32x4){0.f, 0.f, 0.f, 0.f};

  for (int k0 = 0; k0 < K; k0 += 64) {
    #pragma unroll
    for (int i = 0; i < 8; ++i)
      ASYNC_COPY16(As + (i * 32 + wave * 8) * 64, gA + (long long)i * 32 * K + k0);
    #pragma unroll
    for (int i = 0; i < 4; ++i)
      ASYNC_COPY16(Bs + (i * 32 + wave * 8) * 64, gB + (long long)i * 32 * K + k0);
    __syncthreads();
    #pragma unroll
    for (int kk = 0; kk < 2; ++kk) {
      const int slot = ((quad + kk * 4) ^ (l16 & 7)) * 8;
      bf16x8 af[8], bfr[4];
      #pragma unroll
      for (int i = 0; i < 8; ++i)
        af[i] = *(const bf16x8*)&As[(wm + i * 16 + l16) * 64 + slot];
      #pragma unroll
      for (int j = 0; j < 4; ++j)
        bfr[j] = *(const bf16x8*)&Bs[(wn + j * 16 + l16) * 64 + slot];
      #pragma unroll
      for (int i = 0; i < 8; ++i)
        #pragma unroll
        for (int j = 0; j < 4; ++j)
          acc[i][j] = __builtin_amdgcn_mfma_f32_16x16x32_bf16(af[i], bfr[j],
                                                              acc[i][j], 0, 0, 0);
    }
    __syncthreads();
  }

  // epilogue: C/D layout col = lane&15, row = quad*4 + reg; block-uniform route
  #pragma unroll
  for (int j = 0; j < 4; ++j) {
    const int col = n0 + wn + j * 16 + l16;   // 0..1535
    const float bvv = bcat[col];
    #pragma unroll
    for (int i = 0; i < 8; ++i) {
      #pragma unroll
      for (int r = 0; r < 4; ++r) {
        const int row = m0 + wm + i * 16 + quad * 4 + r;
        float x = acc[i][j][r] + bvv;
        if (col < D_MODEL) {
          sigq[(long long)row * D_MODEL + col] = (__bf16)(1.f / (1.f + __expf(-x)));
        } else if (col < 2 * D_MODEL) {
          kb[(long long)row * D_MODEL + (col - D_MODEL)] = (__bf16)x;
        } else {
          vb[(long long)row * D_MODEL + (col - 2 * D_MODEL)] = (__bf16)x;
        }
      }
    }
  }
}

// ------------------------------------------------- transform + transpose
// in : kb,vb [BATCH][SEQ][D] bf16; out: ekvT grouped [BATCH][1024][SEQ]:
// for d: g=d>>5, w=d&31: row g*64+w = exp(k)*v, row g*64+32+w = exp(k).
// 64x64 tile, b128 global I/O both directions, fp32 LDS (+1 pad).
__global__ __launch_bounds__(256) void transform_transpose_kernel(
    const __bf16* __restrict__ kb, const __bf16* __restrict__ vb,
    __bf16* __restrict__ ekvT)
{
  __shared__ float Lekv[64][65];
  __shared__ float Lek[64][65];
  const int b  = blockIdx.z;
  const int s0 = blockIdx.x * 64;
  const int d0 = blockIdx.y * 64;
  const int t  = threadIdx.x;

  // load: thread (r = t>>3, c = t&7) reads bf16x8 at [s0+r(+32h)][d0+c*8]
  const int r = t >> 3;
  const int c = t & 7;
  #pragma unroll
  for (int h = 0; h < 2; ++h) {
    const int sl = h * 32 + r;
    const long long base = ((long long)b * SEQ + s0 + sl) * D_MODEL + d0 + c * 8;
    bf16x8 kk = *(const bf16x8*)(kb + base);
    bf16x8 vv = *(const bf16x8*)(vb + base);
    #pragma unroll
    for (int e = 0; e < 8; ++e) {
      float ek = __expf((float)kk[e]);
      Lek[sl][c * 8 + e]  = ek;
      Lekv[sl][c * 8 + e] = ek * (float)vv[e];
    }
  }
  __syncthreads();

  // store: thread (dl = t>>2, sc = t&3) writes bf16x8 runs along s
  const int dl = t >> 2;
  const int sc = t & 3;
  const int d  = d0 + dl;
  const int gr = ((d >> 5) << 6) + (d & 31);
  __bf16* outp = ekvT + (long long)b * (2 * D_MODEL) * SEQ + s0;
  #pragma unroll
  for (int h = 0; h < 2; ++h) {
    const int sl = h * 32 + sc * 8;
    bf16x8 ev, ee;
    #pragma unroll
    for (int e = 0; e < 8; ++e) {
      ev[e] = (__bf16)Lekv[sl + e][dl];
      ee[e] = (__bf16)Lek[sl + e][dl];
    }
    *(bf16x8*)(outp + (long long)gr * SEQ + sl)        = ev;
    *(bf16x8*)(outp + (long long)(gr + 32) * SEQ + sl) = ee;
  }
}

// -------------------------------------------- einsum + final, fused epilogue
// A = expB [2048][2048]; Bt = ekvT grouped [BATCH][1024][2048].
// acc[i][j] j<2 = num(d), acc[i][j+2] = den(same d).
// out[b*SEQ+t][d] = sigq * num/den  (fp32, written directly).
__global__ __launch_bounds__(256) void einsum_fused_kernel(
    const __bf16* __restrict__ A, const __bf16* __restrict__ BtAll,
    const __bf16* __restrict__ sigq, float* __restrict__ out)
{
  __shared__ __align__(16) __bf16 As[128 * 64];
  __shared__ __align__(16) __bf16 Bs[128 * 64];

  const int b = blockIdx.z;
  const __bf16* Bt = BtAll + (long long)b * (2 * D_MODEL) * SEQ;
  const int K = SEQ;

  const int tid  = threadIdx.x;
  const int wave = tid >> 6;
  const int lane = tid & 63;
  const int quad = lane >> 4;
  const int l16  = lane & 15;
  const int wm   = (wave >> 1) * 64;
  const int wn   = (wave & 1) * 64;
  const int m0 = blockIdx.x * 128;
  const int n0 = blockIdx.y * 128;
  const int l8r = lane >> 3;
  const int scol = ((lane & 7) ^ l8r) * 8;

  const __bf16* ga[4]; const __bf16* gb[4];
  __bf16* la[4]; __bf16* lb[4];
  #pragma unroll
  for (int i = 0; i < 4; ++i) {
    ga[i] = A  + (long long)(m0 + i * 32 + wave * 8 + l8r) * K + scol;
    gb[i] = Bt + (long long)(n0 + i * 32 + wave * 8 + l8r) * K + scol;
    la[i] = As + (i * 32 + wave * 8) * 64;
    lb[i] = Bs + (i * 32 + wave * 8) * 64;
  }

  f32x4 acc[4][4];
  #pragma unroll
  for (int i = 0; i < 4; ++i)
    #pragma unroll
    for (int j = 0; j < 4; ++j) acc[i][j] = (f32x4){0.f, 0.f, 0.f, 0.f};

  for (int k0 = 0; k0 < K; k0 += 64) {
    #pragma unroll
    for (int i = 0; i < 4; ++i) {
      ASYNC_COPY16(la[i], ga[i] + k0);
      ASYNC_COPY16(lb[i], gb[i] + k0);
    }
    __syncthreads();

    #pragma unroll
    for (int kk = 0; kk < 2; ++kk) {
      const int slot = ((quad + kk * 4) ^ (l16 & 7)) * 8;
      bf16x8 af[4], bfr[4];
      #pragma unroll
      for (int i = 0; i < 4; ++i)
        af[i] = *(const bf16x8*)&As[(wm + i * 16 + l16) * 64 + slot];
      #pragma unroll
      for (int j = 0; j < 4; ++j)
        bfr[j] = *(const bf16x8*)&Bs[(wn + j * 16 + l16) * 64 + slot];
      #pragma unroll
      for (int i = 0; i < 4; ++i)
        #pragma unroll
        for (int j = 0; j < 4; ++j)
          acc[i][j] = __builtin_amdgcn_mfma_f32_16x16x32_bf16(af[i], bfr[j],
                                                              acc[i][j], 0, 0, 0);
    }
    __syncthreads();
  }

  const int g = (n0 + wn) >> 6;
  #pragma unroll
  for (int j = 0; j < 2; ++j) {
    const int d = g * 32 + j * 16 + l16;
    #pragma unroll
    for (int i = 0; i < 4; ++i) {
      #pragma unroll
      for (int r = 0; r < 4; ++r) {
        const int row = m0 + wm + i * 16 + quad * 4 + r;
        const long long off = ((long long)b * SEQ + row) * D_MODEL + d;
        const float num = acc[i][j][r];
        const float den = acc[i][j + 2][r];
        out[off] = (float)sigq[off] * (num / den);
      }
    }
  }
}

// ---------------------------------------------------------------- launch
extern "C" void kernel_launch(void* const* d_in, const int* in_sizes, int n_in,
                              void* d_out, int out_size, void* d_ws, size_t ws_size,
                              hipStream_t stream) {
  const float* inputs1 = (const float*)d_in[0];
  const float* inputs2 = (const float*)d_in[1];
  const float* Wq = (const float*)d_in[2];
  const float* bq = (const float*)d_in[3];
  const float* Wk = (const float*)d_in[4];
  const float* bk = (const float*)d_in[5];
  const float* Wv = (const float*)d_in[6];
  const float* bv = (const float*)d_in[7];
  const float* posb = (const float*)d_in[8];
  float* out = (float*)d_out;

  // workspace layout
  char* ws = (char*)d_ws;
  const long long szX  = (long long)ROWS * D_MODEL * 2;            // 16.78 MB
  const long long szW  = (long long)D_MODEL * D_MODEL * 2;         // 0.52 MB
  const long long szEB = (long long)SEQ * SEQ * 2;                 // 8.39 MB
  const long long szT  = (long long)BATCH * 2 * D_MODEL * SEQ * 2; // 33.55 MB
  __bf16* x1b   = (__bf16*)(ws);                 ws += szX;
  __bf16* x2b   = (__bf16*)(ws);                 ws += szX;
  __bf16* wb    = (__bf16*)(ws);                 ws += 3 * szW;
  float*  bcat  = (float*)(ws);                  ws += 3 * D_MODEL * 4;
  __bf16* expBb = (__bf16*)(ws);                 ws += szEB;
  __bf16* sigq  = (__bf16*)(ws);                 ws += szX;
  __bf16* kb    = (__bf16*)(ws);                 ws += szX;
  __bf16* vb    = (__bf16*)(ws);                 ws += szX;
  __bf16* ekvT  = (__bf16*)(ws);                 ws += szT;

  // 1) all converts, one flat launch
  cvt_all_kernel<<<21254, 256, 0, stream>>>(inputs1, inputs2, posb,
                                            Wq, Wk, Wv, bq, bk, bv,
                                            x1b, x2b, expBb, wb, bcat);

  // 2) QKV GEMM: [16384,512] x [1536,512]^T, 256x128 tiles
  {
    dim3 g(ROWS / 256, (3 * D_MODEL) / 128, 1);
    qkv_gemm_kernel<<<g, 256, 0, stream>>>(x1b, x2b, wb, bcat, sigq, kb, vb);
  }

  // 3) transform + transpose -> ekvT grouped [b][1024][S]
  {
    dim3 g(SEQ / 64, D_MODEL / 64, BATCH);
    transform_transpose_kernel<<<g, 256, 0, stream>>>(kb, vb, ekvT);
  }

  // 4) einsum + final fused: per batch [2048,2048]x[1024,2048]^T -> out fp32
  {
    dim3 g(SEQ / 128, (2 * D_MODEL) / 128, BATCH);
    einsum_fused_kernel<<<g, 256, 0, stream>>>(expBb, ekvT, sigq, out);
  }
}

// Round 7
// 264.169 us; speedup vs baseline: 1.0487x; 1.0487x over previous
//
#include <hip/hip_runtime.h>

typedef float  f32x4  __attribute__((ext_vector_type(4)));
typedef __bf16 bf16x8 __attribute__((ext_vector_type(8)));
typedef __bf16 bf16x4 __attribute__((ext_vector_type(4)));

#define D_MODEL 512
#define SEQ     2048
#define BATCH   8
#define ROWS    (BATCH * SEQ)   // 16384

// async 16B global -> LDS (each lane deposits at lds_base + lane*16B)
#define ASYNC_COPY16(dst_lds, src_glb)                                          \
  __builtin_amdgcn_global_load_lds(                                             \
      (const __attribute__((address_space(1))) void*)(src_glb),                 \
      (__attribute__((address_space(3))) void*)(dst_lds), 16, 0, 0)

// ------------------------------------------------------------ fused converts
// flat 1D grid, exact ranges:
// [0,8192) x1->x1b  [8192,16384) x2->x2b  [16384,20480) exp(posb)->expBb
// [20480,21248) Wq|Wk|Wv->wb
__global__ void cvt_all_kernel(const float* __restrict__ x1,
                               const float* __restrict__ x2,
                               const float* __restrict__ posb,
                               const float* __restrict__ Wq,
                               const float* __restrict__ Wk,
                               const float* __restrict__ Wv,
                               __bf16* __restrict__ x1b, __bf16* __restrict__ x2b,
                               __bf16* __restrict__ expBb, __bf16* __restrict__ wb)
{
  const int blk = blockIdx.x;
  if (blk < 16384) {
    const float* in = (blk < 8192) ? x1 : x2;
    __bf16* out = (blk < 8192) ? x1b : x2b;
    const int i = (blk & 8191) * 256 + threadIdx.x;
    float4 v = ((const float4*)in)[i];
    bf16x4 o = { (__bf16)v.x, (__bf16)v.y, (__bf16)v.z, (__bf16)v.w };
    ((bf16x4*)out)[i] = o;
  } else if (blk < 20480) {
    const int i = (blk - 16384) * 256 + threadIdx.x;
    float4 v = ((const float4*)posb)[i];
    bf16x4 o = { (__bf16)__expf(v.x), (__bf16)__expf(v.y),
                 (__bf16)__expf(v.z), (__bf16)__expf(v.w) };
    ((bf16x4*)expBb)[i] = o;
  } else {
    const int i = (blk - 20480) * 256 + threadIdx.x;
    const int nW4 = D_MODEL * D_MODEL / 4;
    const float* src = (i < nW4) ? Wq : (i < 2 * nW4) ? Wk : Wv;
    const int ii = i - ((i < nW4) ? 0 : (i < 2 * nW4) ? nW4 : 2 * nW4);
    float4 v = ((const float4*)src)[ii];
    bf16x4 o = { (__bf16)v.x, (__bf16)v.y, (__bf16)v.z, (__bf16)v.w };
    ((bf16x4*)wb)[i] = o;
  }
}

// ------------------------------------------------------------- tri-GEMM
// One launch, 3 GEMMs (z), all 128x128 tile / BK=64 / einsum resource shape.
// z=0: q    = x1*Wq^T  -> sigmoid -> sigq [rows][d]   (m=rows looped, n=d)
// z=1: kT   = Wk*x1^T  -> + bk    -> kT  [d][rows]    (m=d, n=rows looped)
// z=2: vT   = Wv*x2^T  -> + bv    -> vT  [d][rows]
// T=2 row-tiles per block, seam-pipelined: next tile's first staging is
// issued before the previous tile's epilogue (cold-start overlaps stores).
__global__ __launch_bounds__(256) void tri_gemm_kernel(
    const __bf16* __restrict__ x1b, const __bf16* __restrict__ x2b,
    const __bf16* __restrict__ wb,
    const float* __restrict__ bq, const float* __restrict__ bk,
    const float* __restrict__ bv,
    __bf16* __restrict__ sigq, __bf16* __restrict__ kT,
    __bf16* __restrict__ vT)
{
  __shared__ __align__(16) __bf16 As[128 * 64];
  __shared__ __align__(16) __bf16 Bs[128 * 64];

  const int K = D_MODEL;
  const int z = blockIdx.z;
  const int tid  = threadIdx.x;
  const int wave = tid >> 6;
  const int lane = tid & 63;
  const int quad = lane >> 4;
  const int l16  = lane & 15;
  const int wm   = (wave >> 1) * 64;
  const int wn   = (wave & 1) * 64;
  const int l8r = lane >> 3;
  const int scol = ((lane & 7) ^ l8r) * 8;
  const int F0 = blockIdx.y * 128;              // fixed-dim tile (d side)

  // matrix bases: z=0: A=x1b (looped), B=Wq (fixed)
  //               z=1: A=Wk (fixed),  B=x1b (looped)
  //               z=2: A=Wv (fixed),  B=x2b (looped)
  const __bf16* Ap = (z == 0) ? x1b
                   : (z == 1) ? (wb + (long long)D_MODEL * D_MODEL)
                              : (wb + 2LL * D_MODEL * D_MODEL);
  const __bf16* Bp = (z == 0) ? wb : (z == 1) ? x1b : x2b;

  const int srow = wave * 8 + l8r;              // staging row within 32-group

  // staging pointers for tile t (looped dim L0 = (bx*2+t)*128)
  const __bf16* ga[4]; const __bf16* gb[4];
  auto set_tile = [&](int t) {
    const int L0 = (blockIdx.x * 2 + t) * 128;
    const int m0 = (z == 0) ? L0 : F0;
    const int n0 = (z == 0) ? F0 : L0;
    #pragma unroll
    for (int i = 0; i < 4; ++i) {
      ga[i] = Ap + (long long)(m0 + i * 32 + srow) * K + scol;
      gb[i] = Bp + (long long)(n0 + i * 32 + srow) * K + scol;
    }
  };
  auto stage = [&](int k0) {
    #pragma unroll
    for (int i = 0; i < 4; ++i) {
      ASYNC_COPY16(As + (i * 32 + wave * 8) * 64, ga[i] + k0);
      ASYNC_COPY16(Bs + (i * 32 + wave * 8) * 64, gb[i] + k0);
    }
  };

  set_tile(0);
  stage(0);                                     // cold stage

  for (int t = 0; t < 2; ++t) {
    f32x4 acc[4][4];
    #pragma unroll
    for (int i = 0; i < 4; ++i)
      #pragma unroll
      for (int j = 0; j < 4; ++j) acc[i][j] = (f32x4){0.f, 0.f, 0.f, 0.f};

    for (int k0 = 0; k0 < K; k0 += 64) {
      __syncthreads();                          // staged data ready
      #pragma unroll
      for (int kk = 0; kk < 2; ++kk) {
        const int slot = ((quad + kk * 4) ^ (l16 & 7)) * 8;
        bf16x8 af[4], bfr[4];
        #pragma unroll
        for (int i = 0; i < 4; ++i)
          af[i] = *(const bf16x8*)&As[(wm + i * 16 + l16) * 64 + slot];
        #pragma unroll
        for (int j = 0; j < 4; ++j)
          bfr[j] = *(const bf16x8*)&Bs[(wn + j * 16 + l16) * 64 + slot];
        #pragma unroll
        for (int i = 0; i < 4; ++i)
          #pragma unroll
          for (int j = 0; j < 4; ++j)
            acc[i][j] = __builtin_amdgcn_mfma_f32_16x16x32_bf16(af[i], bfr[j],
                                                                acc[i][j], 0, 0, 0);
      }
      __syncthreads();                          // all waves done reading LDS
      if (k0 + 64 < K) {
        stage(k0 + 64);
      } else if (t == 0) {
        set_tile(1);
        stage(0);                               // overlaps with epilogue below
      }
    }

    // epilogue for tile t: C/D layout col = lane&15, row = quad*4 + reg
    const int L0 = (blockIdx.x * 2 + t) * 128;
    if (z == 0) {
      const int m0 = L0, n0 = F0;
      #pragma unroll
      for (int j = 0; j < 4; ++j) {
        const int col = n0 + wn + j * 16 + l16;       // d
        const float bvv = bq[col];
        #pragma unroll
        for (int i = 0; i < 4; ++i)
          #pragma unroll
          for (int r = 0; r < 4; ++r) {
            const int row = m0 + wm + i * 16 + quad * 4 + r;
            float x = acc[i][j][r] + bvv;
            sigq[(long long)row * D_MODEL + col] =
                (__bf16)(1.f / (1.f + __expf(-x)));
          }
      }
    } else {
      const int m0 = F0, n0 = L0;
      const float* bias = (z == 1) ? bk : bv;
      __bf16* outp = (z == 1) ? kT : vT;
      #pragma unroll
      for (int i = 0; i < 4; ++i) {
        #pragma unroll
        for (int r = 0; r < 4; ++r) {
          const int d = m0 + wm + i * 16 + quad * 4 + r;
          const float bvv = bias[d];
          #pragma unroll
          for (int j = 0; j < 4; ++j) {
            const int rr = n0 + wn + j * 16 + l16;    // global row 0..16383
            outp[(long long)d * ROWS + rr] = (__bf16)(acc[i][j][r] + bvv);
          }
        }
      }
    }
  }
}

// ------------------------------------------------------ streaming combine
// kT,vT [512][16384] bf16 -> ekvT grouped [BATCH][1024][SEQ]:
// for d: g=d>>5, w=d&31: row g*64+w = exp(k)*v, row g*64+32+w = exp(k)
// Pure coalesced bf16x8 I/O, no LDS.
__global__ __launch_bounds__(256) void combine_kernel(
    const __bf16* __restrict__ kT, const __bf16* __restrict__ vT,
    __bf16* __restrict__ ekvT)
{
  const int c = blockIdx.x * 256 + threadIdx.x;   // 16B chunk id, 0..2^20-1
  const int d   = c >> 11;                        // 2048 chunks per d-row
  const int off = (c & 2047) * 8;                 // position in 16384 rows
  const int b = off >> 11;
  const int s = off & 2047;

  bf16x8 kk = *(const bf16x8*)(kT + (long long)d * ROWS + off);
  bf16x8 vv = *(const bf16x8*)(vT + (long long)d * ROWS + off);
  bf16x8 ek, ev;
  #pragma unroll
  for (int e = 0; e < 8; ++e) {
    float ekf = __expf((float)kk[e]);
    ek[e] = (__bf16)ekf;
    ev[e] = (__bf16)(ekf * (float)vv[e]);
  }
  const int gr = ((d >> 5) << 6) + (d & 31);
  __bf16* outp = ekvT + (long long)b * (2 * D_MODEL) * SEQ + s;
  *(bf16x8*)(outp + (long long)gr * SEQ)        = ev;
  *(bf16x8*)(outp + (long long)(gr + 32) * SEQ) = ek;
}

// -------------------------------------------- einsum + final, fused epilogue
// A = expB [2048][2048]; Bt = ekvT grouped [BATCH][1024][2048].
// acc[i][j] j<2 = num(d), acc[i][j+2] = den(same d).
// out[b*SEQ+t][d] = sigq * num/den  (fp32, written directly).
__global__ __launch_bounds__(256) void einsum_fused_kernel(
    const __bf16* __restrict__ A, const __bf16* __restrict__ BtAll,
    const __bf16* __restrict__ sigq, float* __restrict__ out)
{
  __shared__ __align__(16) __bf16 As[128 * 64];
  __shared__ __align__(16) __bf16 Bs[128 * 64];

  const int b = blockIdx.z;
  const __bf16* Bt = BtAll + (long long)b * (2 * D_MODEL) * SEQ;
  const int K = SEQ;

  const int tid  = threadIdx.x;
  const int wave = tid >> 6;
  const int lane = tid & 63;
  const int quad = lane >> 4;
  const int l16  = lane & 15;
  const int wm   = (wave >> 1) * 64;
  const int wn   = (wave & 1) * 64;
  const int m0 = blockIdx.x * 128;
  const int n0 = blockIdx.y * 128;
  const int l8r = lane >> 3;
  const int scol = ((lane & 7) ^ l8r) * 8;

  const __bf16* ga[4]; const __bf16* gb[4];
  __bf16* la[4]; __bf16* lb[4];
  #pragma unroll
  for (int i = 0; i < 4; ++i) {
    ga[i] = A  + (long long)(m0 + i * 32 + wave * 8 + l8r) * K + scol;
    gb[i] = Bt + (long long)(n0 + i * 32 + wave * 8 + l8r) * K + scol;
    la[i] = As + (i * 32 + wave * 8) * 64;
    lb[i] = Bs + (i * 32 + wave * 8) * 64;
  }

  f32x4 acc[4][4];
  #pragma unroll
  for (int i = 0; i < 4; ++i)
    #pragma unroll
    for (int j = 0; j < 4; ++j) acc[i][j] = (f32x4){0.f, 0.f, 0.f, 0.f};

  for (int k0 = 0; k0 < K; k0 += 64) {
    #pragma unroll
    for (int i = 0; i < 4; ++i) {
      ASYNC_COPY16(la[i], ga[i] + k0);
      ASYNC_COPY16(lb[i], gb[i] + k0);
    }
    __syncthreads();

    #pragma unroll
    for (int kk = 0; kk < 2; ++kk) {
      const int slot = ((quad + kk * 4) ^ (l16 & 7)) * 8;
      bf16x8 af[4], bfr[4];
      #pragma unroll
      for (int i = 0; i < 4; ++i)
        af[i] = *(const bf16x8*)&As[(wm + i * 16 + l16) * 64 + slot];
      #pragma unroll
      for (int j = 0; j < 4; ++j)
        bfr[j] = *(const bf16x8*)&Bs[(wn + j * 16 + l16) * 64 + slot];
      #pragma unroll
      for (int i = 0; i < 4; ++i)
        #pragma unroll
        for (int j = 0; j < 4; ++j)
          acc[i][j] = __builtin_amdgcn_mfma_f32_16x16x32_bf16(af[i], bfr[j],
                                                              acc[i][j], 0, 0, 0);
    }
    __syncthreads();
  }

  const int g = (n0 + wn) >> 6;
  #pragma unroll
  for (int j = 0; j < 2; ++j) {
    const int d = g * 32 + j * 16 + l16;
    #pragma unroll
    for (int i = 0; i < 4; ++i) {
      #pragma unroll
      for (int r = 0; r < 4; ++r) {
        const int row = m0 + wm + i * 16 + quad * 4 + r;
        const long long off = ((long long)b * SEQ + row) * D_MODEL + d;
        const float num = acc[i][j][r];
        const float den = acc[i][j + 2][r];
        out[off] = (float)sigq[off] * (num / den);
      }
    }
  }
}

// ---------------------------------------------------------------- launch
extern "C" void kernel_launch(void* const* d_in, const int* in_sizes, int n_in,
                              void* d_out, int out_size, void* d_ws, size_t ws_size,
                              hipStream_t stream) {
  const float* inputs1 = (const float*)d_in[0];
  const float* inputs2 = (const float*)d_in[1];
  const float* Wq = (const float*)d_in[2];
  const float* bq = (const float*)d_in[3];
  const float* Wk = (const float*)d_in[4];
  const float* bk = (const float*)d_in[5];
  const float* Wv = (const float*)d_in[6];
  const float* bv = (const float*)d_in[7];
  const float* posb = (const float*)d_in[8];
  float* out = (float*)d_out;

  // workspace layout
  char* ws = (char*)d_ws;
  const long long szX  = (long long)ROWS * D_MODEL * 2;            // 16.78 MB
  const long long szW  = (long long)D_MODEL * D_MODEL * 2;         // 0.52 MB
  const long long szEB = (long long)SEQ * SEQ * 2;                 // 8.39 MB
  const long long szT  = (long long)BATCH * 2 * D_MODEL * SEQ * 2; // 33.55 MB
  __bf16* x1b   = (__bf16*)(ws);                 ws += szX;
  __bf16* x2b   = (__bf16*)(ws);                 ws += szX;
  __bf16* wb    = (__bf16*)(ws);                 ws += 3 * szW;
  __bf16* expBb = (__bf16*)(ws);                 ws += szEB;
  __bf16* sigq  = (__bf16*)(ws);                 ws += szX;
  __bf16* kT    = (__bf16*)(ws);                 ws += szX;
  __bf16* vT    = (__bf16*)(ws);                 ws += szX;
  __bf16* ekvT  = (__bf16*)(ws);                 ws += szT;

  // 1) all converts, one flat launch
  cvt_all_kernel<<<21248, 256, 0, stream>>>(inputs1, inputs2, posb,
                                            Wq, Wk, Wv,
                                            x1b, x2b, expBb, wb);

  // 2) tri-GEMM: q (row-major) + kT/vT (d-major), T=2 tiles/block
  {
    dim3 g(ROWS / 256, D_MODEL / 128, 3);
    tri_gemm_kernel<<<g, 256, 0, stream>>>(x1b, x2b, wb, bq, bk, bv,
                                           sigq, kT, vT);
  }

  // 3) streaming combine -> ekvT grouped [b][1024][S]
  combine_kernel<<<(D_MODEL * ROWS / 8) / 256, 256, 0, stream>>>(kT, vT, ekvT);

  // 4) einsum + final fused: per batch [2048,2048]x[1024,2048]^T -> out fp32
  {
    dim3 g(SEQ / 128, (2 * D_MODEL) / 128, BATCH);
    einsum_fused_kernel<<<g, 256, 0, stream>>>(expBb, ekvT, sigq, out);
  }
}